// Round 6
// baseline (1751.384 us; speedup 1.0000x reference)
//
#include <hip/hip_runtime.h>
#include <hip/hip_fp16.h>

typedef _Float16 f16;
typedef _Float16 f16x8 __attribute__((ext_vector_type(8)));
typedef float    f32x4 __attribute__((ext_vector_type(4)));

#define HID 512
#define FEA 128
#define ROWSTR 129            // inputs row = 128 feat + 1 shock
#define SEQL 512
#define DEN1 64
#define NG 8                  // batch groups (16 rows each)
#define WPG 32                // workgroups per group
#define MB 16                 // batch rows per group
#define GC 16                 // gate columns per wg
#define THREADS 256
#define KH 512                // recurrent K
#define KX 128                // input K

// workspace layout (bytes); zeroed every launch via hipMemsetAsync
#define WS_CTR    0                     // 64 u32: final-barrier counters (per group)
#define WS_FLG    256                   // NG*32 u32 step flags
#define WS_HRING  4096                  // 2*NG*MB*HID f16 = 262144 B
#define WS_SM     (WS_HRING + 262144)   // 128 f32 shock means
#define WS_HPART  (WS_SM + 1024)        // NG*WPG*MB f32 head partials
#define WS_END    (WS_HPART + 16384)

// ---------- device-coherent (IF$-level, sc0 sc1) asm memory ops — R1-R3-proven tier ----------
__device__ __forceinline__ void st_h2(void* p, unsigned v) {
    asm volatile("global_store_short %0, %1, off sc0 sc1" :: "v"(p), "v"(v) : "memory");
}
__device__ __forceinline__ unsigned long long ld_u64c(const void* p) {
    unsigned long long r;
    asm volatile("global_load_dwordx2 %0, %1, off sc0 sc1" : "=v"(r) : "v"(p));
    asm volatile("s_waitcnt vmcnt(0)" ::: "memory");
    return r;
}
__device__ __forceinline__ unsigned ld_flag32(const unsigned* p) {
    unsigned r;
    asm volatile("global_load_dword %0, %1, off sc0 sc1" : "=v"(r) : "v"(p) : "memory");
    asm volatile("s_waitcnt vmcnt(0)" ::: "memory");
    return r;
}
__device__ __forceinline__ void st_flag32(unsigned* p, unsigned v) {
    asm volatile("global_store_dword %0, %1, off sc0 sc1" :: "v"(p), "v"(v) : "memory");
}
__device__ __forceinline__ void wait_vm0() {
    asm volatile("s_waitcnt vmcnt(0)" ::: "memory");
    __builtin_amdgcn_sched_barrier(0);
}
// raw barriers (no compiler-emitted vmcnt(0) -> wave3's deep x-prefetch stays in flight)
__device__ __forceinline__ void barrier_lgkm() {
    asm volatile("s_waitcnt lgkmcnt(0)" ::: "memory");
    __builtin_amdgcn_sched_barrier(0);
    __builtin_amdgcn_s_barrier();
    __builtin_amdgcn_sched_barrier(0);
    asm volatile("" ::: "memory");
}
__device__ __forceinline__ void barrier_vm0() {
    asm volatile("s_waitcnt vmcnt(0) lgkmcnt(0)" ::: "memory");
    __builtin_amdgcn_sched_barrier(0);
    __builtin_amdgcn_s_barrier();
    __builtin_amdgcn_sched_barrier(0);
    asm volatile("" ::: "memory");
}

__device__ __forceinline__ float sigmoid_f(float x) {
    x = fminf(fmaxf(x, -30.f), 30.f);
    return 1.f / (1.f + __expf(-x));
}
__device__ __forceinline__ float tanh_f(float x) {
    x = fminf(fmaxf(x, -15.f), 15.f);
    float e = __expf(2.f * x);
    return (e - 1.f) / (e + 1.f);
}

__global__ __launch_bounds__(THREADS)
void gru_fused(const float* __restrict__ inp, const float* __restrict__ Wk,
               const float* __restrict__ Rk,  const float* __restrict__ bias,
               const float* __restrict__ W1,  const float* __restrict__ b1,
               const float* __restrict__ gam, const float* __restrict__ bet,
               const float* __restrict__ mmn, const float* __restrict__ mvr,
               const float* __restrict__ W2,  const float* __restrict__ b2p,
               const float* __restrict__ Wsh, float* __restrict__ out,
               char* __restrict__ ws)
{
    __shared__ __align__(16) f16 Bh[KH * 48];   // 49152 B: R gate-col slice as B-frags
    __shared__ __align__(16) f16 Bx[KX * 48];   // 12288 B: Wk gate-col slice as B-frags
    __shared__ float red[2304];                  // 9216 B: gate partials + x-stash dbuf
    // static LDS ~70.7 KB -> 2 blocks/CU capacity: same co-residency regime as R1-R3 (passed)

    const int tid  = threadIdx.x;
    const int g    = blockIdx.x & (NG - 1);   // group
    const int wgk  = blockIdx.x >> 3;         // rank within group, 0..31
    const int lane = tid & 63;
    const int wave = tid >> 6;
    const int j0   = wgk * GC;                // first gate column owned

    unsigned* ctr   = (unsigned*)(ws + WS_CTR);
    unsigned* flg   = (unsigned*)(ws + WS_FLG);
    f16*      hring = (f16*)(ws + WS_HRING);
    float*    smw   = (float*)(ws + WS_SM);
    float*    hpart = (float*)(ws + WS_HPART);

    // ---- stage B-fragments: Bh from Rk (K=512), Bx from Wk (K=128); 48 cols = z|r|h ----
    for (int idx = tid; idx < KH * 48; idx += THREADS) {
        int kk = idx / 48, c = idx - kk * 48;
        int col = (c >> 4) * HID + j0 + (c & 15);
        Bh[((kk >> 3) * 48 + c) * 8 + (kk & 7)] = (f16)Rk[(size_t)kk * 1536 + col];
    }
    for (int idx = tid; idx < KX * 48; idx += THREADS) {
        int kk = idx / 48, c = idx - kk * 48;
        int col = (c >> 4) * HID + j0 + (c & 15);
        Bx[((kk >> 3) * 48 + c) * 8 + (kk & 7)] = (f16)Wk[(size_t)kk * 1536 + col];
    }

    // ---- shock mean: wg with wgk<16 computes batch row g*16+wgk (uses red[0..255]) ----
    if (wgk < MB) {
        int b = g * MB + wgk;
        float a = 0.f;
        for (int t = tid; t < SEQL; t += THREADS)
            a += inp[((size_t)b * SEQL + t) * ROWSTR + FEA];
        red[tid] = a;
        __syncthreads();
        for (int s = THREADS / 2; s > 0; s >>= 1) {
            if (tid < s) red[tid] += red[tid + s];
            __syncthreads();
        }
        if (tid == 0) smw[b] = red[0] * (1.f / SEQL);
    }

    // per-thread constants
    const int brow = tid >> 4;                 // gate-phase row
    const int jcol = j0 + (tid & 15);          // gate-phase col
    const int arow  = lane & 15;               // A-frag row
    const int ahalf = lane >> 4;               // A-frag k-subchunk
    const int lcol  = j0 + (lane & 15);        // MFMA D col for this lane
    const float bZ3  = bias[lcol] + bias[1536 + lcol];                 // folded into x-stash z
    const float bR3  = bias[512 + lcol] + bias[1536 + 512 + lcol];     // folded into x-stash r
    const float bX3  = bias[1024 + lcol];                              // input bias, cand
    const float bHH3 = bias[1536 + 1024 + lcol];                       // recurrent bias, cand

    float xa[4][8];   // wave3: x floats, loaded ~2 steps ahead

    // x-window: convert xa (= x(t+1)), 12 MFMAs, stash x-proj(t+1)+bias, issue x(t+2) loads
    auto x_window = [&](int t) {
        f16x8 afx[4];
        #pragma unroll
        for (int s = 0; s < 4; ++s) {
            f16x8 a;
            #pragma unroll
            for (int q = 0; q < 8; ++q) a[q] = (f16)xa[s][q];
            afx[s] = a;
        }
        f32x4 az = {0,0,0,0}, ar = {0,0,0,0}, ah = {0,0,0,0};
        #pragma unroll
        for (int s = 0; s < 4; ++s) {
            const f16x8* bx = ((const f16x8*)Bx) + (s * 4 + ahalf) * 48 + (lane & 15);
            az = __builtin_amdgcn_mfma_f32_16x16x32_f16(afx[s], bx[0],  az, 0, 0, 0);
            ar = __builtin_amdgcn_mfma_f32_16x16x32_f16(afx[s], bx[16], ar, 0, 0, 0);
            ah = __builtin_amdgcn_mfma_f32_16x16x32_f16(afx[s], bx[32], ah, 0, 0, 0);
        }
        float* xo = red + 768 + ((t + 1) & 1) * 768;
        #pragma unroll
        for (int i = 0; i < 4; ++i) {
            int rix = (ahalf * 4 + i) * 16 + (lane & 15);
            xo[rix]       = az[i] + bZ3;
            xo[256 + rix] = ar[i] + bR3;
            xo[512 + rix] = ah[i] + bX3;
        }
        int tt = (t + 2 < SEQL) ? t + 2 : SEQL - 1;
        const float* xs = inp + ((size_t)(g * MB + arow) * SEQL + tt) * ROWSTR + ahalf * 8;
        #pragma unroll
        for (int s = 0; s < 4; ++s)
            #pragma unroll
            for (int q = 0; q < 8; ++q)
                xa[s][q] = xs[s * 32 + q];
    };

    __syncthreads();   // staging + shock-mean done (required before Bh/Bx reads)

    // wave3: prologue x-stash for t=0 (+ issue x(1) loads)
    if (wave == 3) {
        const float* xs = inp + ((size_t)(g * MB + arow) * SEQL + 0) * ROWSTR + ahalf * 8;
        #pragma unroll
        for (int s = 0; s < 4; ++s)
            #pragma unroll
            for (int q = 0; q < 8; ++q)
                xa[s][q] = xs[s * 32 + q];
        x_window(-1);
    }

    float hold = 0.f;               // own h element (h0 = 0)

    for (int t = 0; t < SEQL; ++t) {
        const int cur = t & 1;

        // ---- main: waves 0-2 compute one gate's h-part over K=512 ----
        if (wave < 3) {
            const f16* hb = hring + ((size_t)cur * NG + g) * MB * HID
                                  + (size_t)arow * HID + ahalf * 8;
            f16x8 af[16];
            #pragma unroll
            for (int s = 0; s < 16; ++s)
                asm volatile("global_load_dwordx4 %0, %1, off offset:%c2 sc0 sc1"
                             : "=v"(af[s]) : "v"(hb), "i"(s * 64));
            wait_vm0();
            f32x4 a0 = {0,0,0,0}, a1 = {0,0,0,0};
            const f16x8* bp = ((const f16x8*)Bh) + ahalf * 48 + wave * GC + (lane & 15);
            #pragma unroll
            for (int s = 0; s < 16; s += 2) {
                a0 = __builtin_amdgcn_mfma_f32_16x16x32_f16(af[s],     bp[s * 192],       a0, 0, 0, 0);
                a1 = __builtin_amdgcn_mfma_f32_16x16x32_f16(af[s + 1], bp[(s + 1) * 192], a1, 0, 0, 0);
            }
            f32x4 acc = a0 + a1;
            float badd = (wave == 2) ? bHH3 : 0.f;
            #pragma unroll
            for (int i = 0; i < 4; ++i)
                red[wave * 256 + (ahalf * 4 + i) * 16 + (lane & 15)] = acc[i] + badd;
        }
        barrier_lgkm();   // gate partials + (t=0) x-stash visible; wave3 x loads in flight

        // ---- gates: all 256 threads; element (brow, jcol) ----
        {
            float hzs = red[tid];
            float hrs = red[256 + tid];
            float hhs = red[512 + tid];
            const float* xi = red + 768 + (t & 1) * 768;
            float xzs = xi[tid], xrs = xi[256 + tid], xhs = xi[512 + tid];
            float z = sigmoid_f(hzs + xzs);
            float r = sigmoid_f(hrs + xrs);
            float hc = tanh_f(xhs + r * hhs);
            float hnew = z * hold + (1.f - z) * hc;
            f16 h16 = (f16)hnew;
            hold = (float)h16;
            union { f16 h; unsigned short u; } cv; cv.h = h16;
            st_h2(hring + (((size_t)(cur ^ 1) * NG + g) * MB + brow) * HID + jcol,
                  (unsigned)cv.u);
        }
        barrier_vm0();    // ALL waves' h-stores drained to coherence point

        // ---- window: wave0 flag+poll; wave3 x-proj(t+1) overlapped with the poll ----
        if (wave == 0) {
            unsigned* fg = flg + g * 32;
            if (lane == 0) st_flag32(fg + wgk, (unsigned)(t + 1));
            const unsigned want = (unsigned)(t + 1);
            for (;;) {
                unsigned v = ld_flag32(fg + (lane & 31));
                if (__all((int)(v >= want))) break;
            }
        } else if (wave == 3) {
            x_window(t);
        }
        barrier_lgkm();   // x-stash visible; everyone may advance
    }

    // ---- head: state=(h + shock_mean*W_shock); relu(state@W1+b1); BN; @W2+b2 ----
    // final h in ring slot 0 (t=511 wrote cur^1 = 0)
    const f16* hf = hring + ((size_t)g * MB + brow) * HID;
    const int sub = tid & 15;
    const int c0 = wgk * 2;          // this wg's two DENSE1 columns
    float p0 = 0.f, p1 = 0.f, w0 = 0.f, w1 = 0.f;
    for (int c8 = 0; c8 < 8; ++c8) {
        union { unsigned long long u; f16 h[4]; } x;
        x.u = ld_u64c(hf + sub * 32 + c8 * 4);
        #pragma unroll
        for (int e = 0; e < 4; ++e) {
            int k = sub * 32 + c8 * 4 + e;
            float hv = (float)x.h[e];
            float a0 = W1[(size_t)k * DEN1 + c0];
            float a1 = W1[(size_t)k * DEN1 + c0 + 1];
            p0 += hv * a0; p1 += hv * a1; w0 += a0; w1 += a1;
        }
    }
    __syncthreads();   // red reuse safe
    red[tid] = p0; red[256 + tid] = w0; red[512 + tid] = p1; red[768 + tid] = w1;
    __syncthreads();
    if (tid < 32) {
        int b = tid >> 1, cc = tid & 1;
        int c = c0 + cc;
        float dot = 0.f, wsum = 0.f;
        for (int i = 0; i < 16; ++i) {
            dot  += red[cc * 512 + b * 16 + i];
            wsum += red[cc * 512 + 256 + b * 16 + i];
        }
        float sW = smw[g * MB + b] * Wsh[0];
        float d = dot + sW * wsum + b1[c];
        d = fmaxf(d, 0.f);
        d = (d - mmn[c]) * rsqrtf(mvr[c] + 0.001f) * gam[c] + bet[c];
        red[1024 + tid] = d * W2[c];
    }
    __syncthreads();
    if (tid < MB)
        hpart[((size_t)g * WPG + wgk) * MB + tid] = red[1024 + tid * 2] + red[1024 + tid * 2 + 1];
    __syncthreads();
    // final heavy barrier (once): full fences so plain loads of smw/hpart are fresh
    if (tid == 0) {
        __builtin_amdgcn_fence(__ATOMIC_RELEASE, "agent");
        unsigned* c9 = ctr + g;
        unsigned old = __hip_atomic_fetch_add(c9, 1u, __ATOMIC_RELAXED, __HIP_MEMORY_SCOPE_AGENT);
        if (old != WPG - 1)
            while (__hip_atomic_load(c9, __ATOMIC_RELAXED, __HIP_MEMORY_SCOPE_AGENT) < WPG) {}
        __builtin_amdgcn_fence(__ATOMIC_ACQUIRE, "agent");
    }
    __syncthreads();
    if (wgk == 0 && tid < MB) {
        float o = b2p[0];
        for (int k = 0; k < WPG; ++k)       // fixed order -> deterministic
            o += hpart[((size_t)g * WPG + k) * MB + tid];
        out[g * MB + tid] = o;
    }
}

extern "C" void kernel_launch(void* const* d_in, const int* in_sizes, int n_in,
                              void* d_out, int out_size, void* d_ws, size_t ws_size,
                              hipStream_t stream) {
    (void)in_sizes; (void)n_in; (void)out_size; (void)ws_size;
    const float* inp  = (const float*)d_in[0];
    const float* Wk   = (const float*)d_in[1];
    const float* Rk   = (const float*)d_in[2];
    const float* bias = (const float*)d_in[3];
    const float* W1   = (const float*)d_in[4];
    const float* b1   = (const float*)d_in[5];
    const float* gam  = (const float*)d_in[6];
    const float* bet  = (const float*)d_in[7];
    const float* mmn  = (const float*)d_in[8];
    const float* mvr  = (const float*)d_in[9];
    const float* W2   = (const float*)d_in[10];
    const float* b2p  = (const float*)d_in[11];
    const float* Wsh  = (const float*)d_in[12];

    hipMemsetAsync(d_ws, 0, WS_END, stream);   // flags/counters + h0 = 0, every launch
    hipLaunchKernelGGL(gru_fused, dim3(NG * WPG), dim3(THREADS), 0, stream,
                       inp, Wk, Rk, bias, W1, b1, gam, bet, mmn, mvr, W2, b2p, Wsh,
                       (float*)d_out, (char*)d_ws);
}